// Round 1
// 58.085 us; speedup vs baseline: 1.0364x; 1.0364x over previous
//
#include <hip/hip_runtime.h>

#define NQ 12
#define NT 64   // one wave per block, one batch element per block

// ---------------------------------------------------------------------------
// Transfer-matrix evaluation. Math identical to the verified R13/current
// kernel (absmax 4.88e-4); remapped to 1 element per 64-lane wave:
//   - prefix chain (lanes 0-15) and TRANSPOSED suffix chain (lanes 16-31)
//     run in the same 9 uniform shuffle-matmul steps
//   - Rv boundary vectors on lanes 32-63
//   - site objects: 3 rounds (3 groups x 3 qubits) instead of 9
//   - fast __cosf/__sinf (all angles small; v_sin/v_cos accurate here)
// ---------------------------------------------------------------------------

struct cpx { float x, y; };
__device__ __forceinline__ cpx cmul(cpx a, cpx b) {
    return { a.x * b.x - a.y * b.y, a.x * b.y + a.y * b.x };
}
__device__ __forceinline__ cpx cmulc(cpx a, cpx b) {   // a * conj(b)
    return { a.x * b.x + a.y * b.y, a.y * b.x - a.x * b.y };
}
__device__ __forceinline__ cpx cadd(cpx a, cpx b) { return { a.x + b.x, a.y + b.y }; }
__device__ __forceinline__ cpx csub(cpx a, cpx b) { return { a.x - b.x, a.y - b.y }; }
__device__ __forceinline__ cpx shflc(cpx a, int lane) {
    cpx r; r.x = __shfl(a.x, lane, 64); r.y = __shfl(a.y, lane, 64); return r;
}

__global__ __launch_bounds__(NT) void qsim_kernel(
    const float* __restrict__ x,   // (B, 12) fp32
    const float* __restrict__ w,   // (2, 12, 3) fp32
    float* __restrict__ out)       // (B, 12) fp32
{
    __shared__ float fm[2][NQ][8];
    __shared__ cpx Amat[9][16], Bmat[9][16];
    __shared__ cpx gS[4][4];
    __shared__ cpx h0U[4], h0S[4], h11U[4], h11S[4];
    __shared__ cpx Rv[3][4][4];
    __shared__ cpx PBc[11][16];
    __shared__ cpx SAc[12][16];

    const int t   = threadIdx.x;
    const int u   = t & 15;        // entry index within 16-lane group
    const int grp = t >> 4;
    const int b   = blockIdx.x;    // one batch element per block

    // ---- Phase 1: fused gate matrices, 24 tasks on lanes 0..23 ----
    if (t < 2 * NQ) {
        const int l = (t >= NQ) ? 1 : 0;
        const int q = t - l * NQ;
        float hy = 0.5f * x[b * NQ + q];
        float cy = __cosf(hy), sy = __sinf(hy);
        const float* wp = w + (l * NQ + q) * 3;
        float phi = wp[0], the = wp[1], om = wp[2];
        float cth = __cosf(0.5f * the), sth = __sinf(0.5f * the);
        float al = 0.5f * (phi + om), be = 0.5f * (phi - om);
        float ca = __cosf(al), sa = __sinf(al), cb = __cosf(be), sb = __sinf(be);
        float r00r =  ca * cth, r00i = -sa * cth;
        float r01r = -cb * sth, r01i = -sb * sth;
        float r10r =  cb * sth, r10i = -sb * sth;
        float r11r =  ca * cth, r11i =  sa * cth;
        float* m = fm[l][q];
        m[0] =  r00r * cy + r01r * sy;  m[1] =  r00i * cy + r01i * sy;  // U00
        m[2] = -r00r * sy + r01r * cy;  m[3] = -r00i * sy + r01i * cy;  // U01
        m[4] =  r10r * cy + r11r * sy;  m[5] =  r10i * cy + r11i * sy;  // U10
        m[6] = -r10r * sy + r11r * cy;  m[7] = -r10i * sy + r11i * cy;  // U11
    }
    __syncthreads();

    auto Vq = [&](int q, int bit) -> cpx {
        const float* m = &fm[0][q][bit ? 4 : 0]; return { m[0], m[1] };
    };
    auto Uq = [&](int q, int d, int c) -> cpx {
        const float* m = &fm[1][q][4 * d + 2 * c]; return { m[0], m[1] };
    };

    // ---- Phase 2: site objects (groups 0-2: 3 qubits each), gS+h (group 3) ----
    const int a = (u >> 3) & 1, ap = (u >> 2) & 1, c = (u >> 1) & 1, cp = u & 1;
    if (grp < 3) {
        #pragma unroll
        for (int r = 0; r < 3; ++r) {
            const int q = 2 + 3 * grp + r;          // covers q = 2..10
            cpx t0 = cmul(Vq(q, c ^ a),  Uq(q, 0, c));
            cpx t1 = cmul(Vq(q, c ^ a),  Uq(q, 1, c));
            cpx p0 = cmul(Vq(q, cp ^ ap), Uq(q, 0, cp));
            cpx p1 = cmul(Vq(q, cp ^ ap), Uq(q, 1, cp));
            cpx e0 = cmulc(t0, p0), e1 = cmulc(t1, p1);
            Amat[q - 2][u] = cadd(e0, e1);
            Bmat[q - 2][u] = csub(e0, e1);
        }
    } else {
        const int s = a, sp = ap, cc = c, ccp = cp;
        cpx l0 = cmul(Uq(1, 0, cc),  Vq(1, cc ^ s));
        cpx l1 = cmul(Uq(1, 1, cc),  Vq(1, cc ^ s));
        cpx m0 = cmul(Uq(1, 0, ccp), Vq(1, ccp ^ sp));
        cpx m1 = cmul(Uq(1, 1, ccp), Vq(1, ccp ^ sp));
        cpx gg = csub(cmulc(l0, m0), cmulc(l1, m1));
        cpx lw = cmulc(Vq(0, s), Vq(0, sp));
        gS[2 * s + sp][2 * cc + ccp] = cmul(gg, lw);
        if (u < 4) {
            const int c0 = u >> 1, c0p = u & 1;
            cpx a0 = cmulc(Uq(0, 0, c0),  Uq(0, 0, c0p));
            cpx a1 = cmulc(Uq(0, 1, c0),  Uq(0, 1, c0p));
            h0U[u] = cadd(a0, a1);  h0S[u] = csub(a0, a1);
            cpx b0v = cmulc(Uq(11, 0, c0),  Uq(11, 0, c0p));
            cpx b1v = cmulc(Uq(11, 1, c0),  Uq(11, 1, c0p));
            h11U[u] = cadd(b0v, b1v);  h11S[u] = csub(b0v, b1v);
        }
    }
    __syncthreads();

    // ---- Phase 3: both chains in 9 uniform steps (lanes 0-31), Rv (32-63) ----
    if (t < 32) {
        const int R = u >> 2, C = u & 3;
        const bool isA = (t >= 16);        // suffix chain, stored transposed
        const int base = t & 48;           // 0 or 16
        // Preload step matrices into registers (static indices -> VGPRs).
        // prefix:  PB_k    = PB_{k-1}   * B_k    (k = 2..10,  M_i = B[i])
        // suffix:  SA^T_k  = SA^T_{k+1} * A_k^T  (k = 10..2,  M_i(K,C) = A[8-i](C,K))
        cpx rhs[9][4];
        #pragma unroll
        for (int i = 0; i < 9; ++i)
            #pragma unroll
            for (int K = 0; K < 4; ++K)
                rhs[i][K] = isA ? Amat[8 - i][4 * C + K] : Bmat[i][4 * K + C];
        cpx cur = { (R == C) ? 1.f : 0.f, 0.f };
        { cpx* dst = isA ? &SAc[11][4 * C + R] : &PBc[1][u]; *dst = cur; }  // identity
        #pragma unroll
        for (int i = 0; i < 9; ++i) {
            cpx nv = { 0.f, 0.f };
            #pragma unroll
            for (int K = 0; K < 4; ++K)
                nv = cadd(nv, cmul(shflc(cur, base + 4 * R + K), rhs[i][K]));
            cur = nv;
            // suffix lane u=(R,C) holds SA^T(R,C) = SA(C,R) -> scatter-store
            cpx* dst = isA ? &SAc[10 - i][4 * C + R] : &PBc[2 + i][u];
            *dst = cur;
        }
    } else {
        // Right boundary vectors: 48 tasks on 32 lanes (V = task>>4)
        for (int task = t - 32; task < 48; task += 32) {
            const int V = task >> 4, uu = task & 15;
            const int s = (uu >> 3) & 1, sp = (uu >> 2) & 1;
            const int c10 = (uu >> 1) & 1, c10p = uu & 1;
            const cpx* h0  = (V == 1) ? h0U  : h0S;
            const cpx* h11 = (V == 0) ? h11U : h11S;
            cpx acc = { 0.f, 0.f };
            #pragma unroll
            for (int c0 = 0; c0 < 2; ++c0)
                #pragma unroll
                for (int c0p = 0; c0p < 2; ++c0p) {
                    cpx term = cmul(h0[2 * c0 + c0p], h11[2 * (c0 ^ s) + (c0p ^ sp)]);
                    term = cmul(term, Vq(11, c0 ^ s ^ c10));
                    term = cmulc(term, Vq(11, c0p ^ sp ^ c10p));
                    acc = cadd(acc, term);
                }
            Rv[V][2 * s + sp][2 * c10 + c10p] = acc;
        }
    }
    __syncthreads();

    // ---- Phase 4: finals, 48 tasks on 64 lanes, quad shfl-reduce, store ----
    if (t < 48) {
        const int qq = t >> 2, ssi = t & 3;
        const int kk = (qq == 0 || qq == 11) ? 10 : qq;
        const int V  = (qq == 0) ? 1 : ((qq == 11) ? 2 : 0);
        cpx rowL[4], colR[4];
        #pragma unroll
        for (int K = 0; K < 4; ++K) {
            cpx acc = { 0.f, 0.f };
            #pragma unroll
            for (int R = 0; R < 4; ++R)
                acc = cadd(acc, cmul(gS[ssi][R], PBc[kk][4 * R + K]));
            rowL[K] = acc;
            cpx acc2 = { 0.f, 0.f };
            #pragma unroll
            for (int C = 0; C < 4; ++C)
                acc2 = cadd(acc2, cmul(SAc[kk + 1][4 * K + C], Rv[V][ssi][C]));
            colR[K] = acc2;
        }
        cpx val = { 0.f, 0.f };
        #pragma unroll
        for (int K = 0; K < 4; ++K) val = cadd(val, cmul(rowL[K], colR[K]));
        float vr = val.x;                       // real up to fp noise
        vr += __shfl_xor(vr, 1, 64);            // sum the 4 ssi variants
        vr += __shfl_xor(vr, 2, 64);
        if ((t & 3) == 0) out[b * NQ + (t >> 2)] = vr;
    }
}

extern "C" void kernel_launch(void* const* d_in, const int* in_sizes, int n_in,
                              void* d_out, int out_size, void* d_ws, size_t ws_size,
                              hipStream_t stream) {
    int xi = 0, wi = 1;
    if (n_in >= 2 && in_sizes[1] > in_sizes[0]) { xi = 1; wi = 0; }
    const float* x = (const float*)d_in[xi];
    const float* w = (const float*)d_in[wi];
    float* out = (float*)d_out;
    const int B = in_sizes[xi] / NQ;   // 1024
    qsim_kernel<<<B, NT, 0, stream>>>(x, w, out);
}